// Round 26
// baseline (481.425 us; speedup 1.0000x reference)
//
#include <hip/hip_runtime.h>
#include <hip/hip_fp16.h>

#define NEG_SLOPE 0.2f

using f16x8 = __attribute__((ext_vector_type(8))) _Float16;
using f32x4 = __attribute__((ext_vector_type(4))) float;

__device__ __forceinline__ float leakyf(float x) { return x >= 0.f ? x : NEG_SLOPE * x; }

__device__ __forceinline__ void gload_lds16(const void* g, void* l) {
    __builtin_amdgcn_global_load_lds(
        (const __attribute__((address_space(1))) unsigned int*)g,
        (__attribute__((address_space(3))) unsigned int*)l, 16, 0, 0);
}

#define MFMA16(a, b, c) __builtin_amdgcn_mfma_f32_16x16x32_f16(a, b, c, 0, 0, 0)

// ===== prelude1: fn | inc_hist | code_hist | prep_weights (independent) =====
__global__ __launch_bounds__(256)
void prelude1_kernel(const float* __restrict__ v, const int* __restrict__ f,
                     float4* __restrict__ fn4, int NF, int NE,
                     unsigned* __restrict__ gh, int fnB, int ihB, int chB,
                     int* __restrict__ codes, int* __restrict__ hist, int M,
                     const float* __restrict__ Wconv, const float* __restrict__ Wlfc,
                     const float* __restrict__ W2, const float* __restrict__ W3,
                     __half* __restrict__ wpadh, __half* __restrict__ wlfch,
                     __half* __restrict__ w2h, __half* __restrict__ w3h) {
    __shared__ unsigned h[1024];
    const int t = threadIdx.x;
    int b = blockIdx.x;
    if (b < fnB) {
        int i = b * 256 + t;
        if (i >= NF) return;
        int i0 = f[3 * i], i1 = f[3 * i + 1], i2 = f[3 * i + 2];
        float p0x = v[3 * i0], p0y = v[3 * i0 + 1], p0z = v[3 * i0 + 2];
        float ux = v[3 * i1] - p0x, uy = v[3 * i1 + 1] - p0y, uz = v[3 * i1 + 2] - p0z;
        float wx = v[3 * i2] - p0x, wy = v[3 * i2 + 1] - p0y, wz = v[3 * i2 + 2] - p0z;
        fn4[i] = make_float4(uy * wz - uz * wy, uz * wx - ux * wz, ux * wy - uy * wx, 0.f);
    } else if (b < fnB + ihB) {
        int blk = b - fnB;
        h[t] = 0; h[t + 256] = 0; h[t + 512] = 0; h[t + 768] = 0;
        __syncthreads();
        int base = blk * 4096;
#pragma unroll
        for (int k = 0; k < 16; ++k) {
            int idx = base + k * 256 + t;
            if (idx < NE) atomicAdd(&h[((unsigned)f[idx]) >> 8], 1u);
        }
        __syncthreads();
#pragma unroll
        for (int k = 0; k < 4; ++k) { int bb = t + k * 256; gh[(size_t)blk * 1024 + bb] = h[bb]; }
    } else if (b < fnB + ihB + chB) {
        int i = (b - fnB - ihB) * 256 + t;
        if (i >= M) return;
        int cx = min(max((int)((v[3 * i + 0] + 1.f) * 8.f), 0), 15);
        int cy = min(max((int)((v[3 * i + 1] + 1.f) * 8.f), 0), 15);
        int cz = min(max((int)((v[3 * i + 2] + 1.f) * 8.f), 0), 15);
        int code = 0;
#pragma unroll
        for (int bb = 0; bb < 4; ++bb)
            code |= (((cx >> bb) & 1) << (3 * bb)) | (((cy >> bb) & 1) << (3 * bb + 1)) |
                    (((cz >> bb) & 1) << (3 * bb + 2));
        codes[i] = code;
        atomicAdd(&hist[code], 1);
    } else {
        int bw = b - fnB - ihB - chB;
        if (bw < 64) {
            int i = bw * 256 + t; int ch = i >> 7, k = i & 127;
            wpadh[i] = __float2half(k < 125 ? Wconv[ch * 125 + k] : 0.f);
        } else if (bw < 128) {
            int i = (bw - 64) * 256 + t; wlfch[i] = __float2half(Wlfc[i]);
        } else if (bw < 640) {
            int i = (bw - 128) * 256 + t; w2h[i] = __float2half(W2[i]);
        } else {
            int i = (bw - 640) * 256 + t; w3h[i] = __float2half(W3[i]);
        }
    }
}

// ===== prelude2: per-bin row scan (blocks 0..1023) | morton hist scan (block 1024) =====
__global__ __launch_bounds__(256)
void prelude2_kernel(unsigned* __restrict__ gh, unsigned* __restrict__ binTotals, int NB,
                     const int* __restrict__ hist, int* __restrict__ offs) {
    __shared__ unsigned s[256];
    __shared__ unsigned carrySh;
    const int t = threadIdx.x;
    if (blockIdx.x < 1024) {
        const int bin = blockIdx.x;
        if (t == 0) carrySh = 0;
        __syncthreads();
        for (int base = 0; base < NB; base += 256) {
            unsigned c = carrySh;
            int i = base + t;
            unsigned val = (i < NB) ? gh[(size_t)i * 1024 + bin] : 0;
            s[t] = val;
            __syncthreads();
            for (int d = 1; d < 256; d <<= 1) {
                unsigned x = (t >= d) ? s[t - d] : 0;
                __syncthreads();
                s[t] += x;
                __syncthreads();
            }
            if (i < NB) gh[(size_t)i * 1024 + bin] = s[t] - val + c;
            if (t == 255) carrySh = c + s[255];
            __syncthreads();
        }
        if (t == 0) binTotals[bin] = carrySh;
    } else {
        if (t == 0) carrySh = 0;
        __syncthreads();
        for (int base = 0; base < 4096; base += 256) {
            unsigned c = carrySh;
            unsigned val = (unsigned)hist[base + t];
            s[t] = val;
            __syncthreads();
            for (int d = 1; d < 256; d <<= 1) {
                unsigned x = (t >= d) ? s[t - d] : 0;
                __syncthreads();
                s[t] += x;
                __syncthreads();
            }
            offs[base + t] = (int)(s[t] - val + c);
            if (t == 255) carrySh = c + s[255];
            __syncthreads();
        }
    }
}

// ===== prelude3: bin scan (block 0) | morton scatter (blocks 1..) =====
__global__ __launch_bounds__(256)
void prelude3_kernel(const unsigned* __restrict__ binTotals, unsigned* __restrict__ binstart,
                     const int* __restrict__ codes, int* __restrict__ offs,
                     int* __restrict__ perm, int M) {
    __shared__ unsigned s[256];
    __shared__ unsigned carrySh;
    const int t = threadIdx.x;
    if (blockIdx.x == 0) {
        if (t == 0) carrySh = 0;
        __syncthreads();
        for (int base = 0; base < 1024; base += 256) {
            unsigned c = carrySh;
            unsigned val = binTotals[base + t];
            s[t] = val;
            __syncthreads();
            for (int d = 1; d < 256; d <<= 1) {
                unsigned x = (t >= d) ? s[t - d] : 0;
                __syncthreads();
                s[t] += x;
                __syncthreads();
            }
            binstart[base + t] = s[t] - val + c;
            if (t == 255) carrySh = c + s[255];
            __syncthreads();
        }
        if (t == 0) binstart[1024] = carrySh;
    } else {
        int i = (blockIdx.x - 1) * 256 + t;
        if (i >= M) return;
        int pos = atomicAdd(&offs[codes[i]], 1);
        perm[pos] = i;
    }
}

// ===== incidence scatter (needs gh + binstart) =====
__global__ __launch_bounds__(256)
void inc_scatter_kernel(const int* __restrict__ f, const unsigned* __restrict__ gh,
                        const unsigned* __restrict__ binstart,
                        unsigned* __restrict__ sortedV, unsigned* __restrict__ sortedE,
                        int NE) {
    __shared__ unsigned loc[1024];
    const int t = threadIdx.x, blk = blockIdx.x;
#pragma unroll
    for (int k = 0; k < 4; ++k) {
        int b = t + k * 256;
        loc[b] = gh[(size_t)blk * 1024 + b] + binstart[b];
    }
    __syncthreads();
    int base = blk * 4096;
#pragma unroll
    for (int k = 0; k < 16; ++k) {
        int idx = base + k * 256 + t;
        if (idx < NE) {
            unsigned vv = (unsigned)f[idx];
            unsigned pos = atomicAdd(&loc[vv >> 8], 1u);
            sortedV[pos] = vv;
            sortedE[pos] = (unsigned)idx;
        }
    }
}

// ---- per-bin gather: LDS float accumulate, coalesced non-atomic vn write ----
__global__ __launch_bounds__(256)
void vn_gather_kernel(const unsigned* __restrict__ sortedV, const unsigned* __restrict__ sortedE,
                      const float4* __restrict__ fn4, const unsigned* __restrict__ binstart,
                      float* __restrict__ vn, int M) {
    __shared__ float acc[768];
    const int t = threadIdx.x, b = blockIdx.x;
    acc[t] = 0.f; acc[t + 256] = 0.f; acc[t + 512] = 0.f;
    __syncthreads();
    unsigned s = binstart[b], e = binstart[b + 1];
    for (unsigned i = s + t; i < e; i += 256) {
        unsigned vv = sortedV[i];
        float4 fn = fn4[sortedE[i] / 3];
        int lv = (int)(vv & 255u) * 3;
        atomicAdd(&acc[lv + 0], fn.x);
        atomicAdd(&acc[lv + 1], fn.y);
        atomicAdd(&acc[lv + 2], fn.z);
    }
    __syncthreads();
    int gv = b * 256 + t;
    if (gv < M) {
        vn[3 * gv + 0] = acc[t * 3 + 0];
        vn[3 * gv + 1] = acc[t * 3 + 1];
        vn[3 * gv + 2] = acc[t * 3 + 2];
    }
}

// ------- trilinear 5x5x5 sampling: separable params + LDS bbox staging -------
__global__ __launch_bounds__(256)
void sample_kernel(const float* __restrict__ v, const float* __restrict__ vol,
                   const int* __restrict__ perm,
                   __half* __restrict__ cubes, int m_start, int cnt, int nwg, int scatter) {
    __shared__ float bbox[2][448];
    __shared__ int pi0[2][16];
    __shared__ float pw[2][16];
    const int half = threadIdx.x >> 7;
    const int q = threadIdx.x & 127;
    int q8 = nwg >> 3, r8 = nwg & 7;
    int xcd = blockIdx.x & 7, idxb = blockIdx.x >> 3;
    int bid = (xcd < r8 ? xcd * (q8 + 1) : r8 * (q8 + 1) + (xcd - r8) * q8) + idxb;
    int ml = bid * 2 + half;
    bool valid = ml < cnt;
    int m = valid ? perm[m_start + ml] : 0;

    if (valid && q < 15) {
        int axis = q / 5, idx = q - 5 * axis;
        float g = -3.f + 1.25f * (float)idx;
        float p = v[3 * m + axis] + g / 192.f * 2.f;
        float pos = fminf(fmaxf((p + 1.f) * 0.5f * 191.f, 0.f), 191.f);
        float fl = floorf(pos);
        pi0[half][q] = (int)fl;
        pw[half][q] = pos - fl;
    }
    __syncthreads();
    if (valid) {
        int xlo = pi0[half][0], ylo = pi0[half][5], zlo = pi0[half][10];
        int j = q & 63;
        int dy = j >> 3, dx = j & 7;
        if (dy < 7) {
            int X = min(xlo + dx, 191);
            int Y = min(ylo + dy, 191);
            int rowoff = dy * 9 + dx;
            const float* volYX = vol + Y * 192 + X;
#pragma unroll
            for (int k = 0; k < 4; ++k) {
                int pz = (q >> 6) + k * 2;
                if (pz < 7) {
                    int Z = min(zlo + pz, 191);
                    bbox[half][pz * 63 + rowoff] = volYX[Z * 36864];
                }
            }
        }
    }
    __syncthreads();
    if (!valid) return;
    __half* dst = cubes + (size_t)(scatter ? m : ml) * 128;
    if (q >= 125) { dst[q] = __float2half(0.f); return; }
    int a = q % 5, b = (q / 5) % 5, c = q / 25;
    int xlo = pi0[half][0], ylo = pi0[half][5], zlo = pi0[half][10];
    int gx0 = pi0[half][a], gy0 = pi0[half][5 + b], gz0 = pi0[half][10 + c];
    float wxv = pw[half][a], wyv = pw[half][5 + b], wzv = pw[half][10 + c];
    int x0 = gx0 - xlo, y0 = gy0 - ylo, z0 = gz0 - zlo;
    int x1 = min(gx0 + 1, 191) - xlo;
    int y1 = min(gy0 + 1, 191) - ylo;
    int z1 = min(gz0 + 1, 191) - zlo;
    const float* bb = bbox[half];
    int b00 = z0 * 63 + y0 * 9, b01 = z0 * 63 + y1 * 9;
    int b10 = z1 * 63 + y0 * 9, b11 = z1 * 63 + y1 * 9;
    float c000 = bb[b00 + x0], c001 = bb[b00 + x1];
    float c010 = bb[b01 + x0], c011 = bb[b01 + x1];
    float c100 = bb[b10 + x0], c101 = bb[b10 + x1];
    float c110 = bb[b11 + x0], c111 = bb[b11 + x1];
    float omx = 1.f - wxv, omy = 1.f - wyv, omz = 1.f - wzv;
    float c00 = c000 * omx + c001 * wxv;
    float c01 = c010 * omx + c011 * wxv;
    float c10 = c100 * omx + c101 * wxv;
    float c11 = c110 * omx + c111 * wxv;
    float c0 = c00 * omy + c01 * wyv;
    float c1 = c10 * omy + c11 * wyv;
    dst[25 * a + 5 * b + c] = __float2half(c0 * omz + c1 * wzv);
}

// ---- z_point = leaky([v, vn_norm] @ W1^T + b1) -> zcat cols [0:128) fp16 ----
__global__ __launch_bounds__(256)
void point_kernel(const float* __restrict__ v, const float* __restrict__ vn,
                  const int* __restrict__ pvec,
                  const float* __restrict__ W1, const float* __restrict__ b1,
                  __half* __restrict__ zcat, int m_start, int cnt) {
    int ml = blockIdx.x * 2 + (threadIdx.x >> 7);
    if (ml >= cnt) return;
    int n = threadIdx.x & 127;
    int m = pvec ? pvec[m_start + ml] : (m_start + ml);
    float x0 = v[3 * m], x1 = v[3 * m + 1], x2 = v[3 * m + 2];
    float nx = vn[3 * m], ny = vn[3 * m + 1], nz = vn[3 * m + 2];
    float nrm = fmaxf(sqrtf(nx * nx + ny * ny + nz * nz), 1e-6f);
    nx /= nrm; ny /= nrm; nz /= nrm;
    const float* w = W1 + n * 6;
    float z = b1[n] + x0 * w[0] + x1 * w[1] + x2 * w[2] + nx * w[3] + ny * w[4] + nz * w[5];
    zcat[(size_t)ml * 256 + n] = __float2half(leakyf(z));
}

// -------- fused conv+lfc: z_local = leaky(leaky(cubes@WconvT+bc)@WlfcT+bl) --------
__global__ __launch_bounds__(256)
void convlfc_kernel(const __half* __restrict__ cubes, const __half* __restrict__ wconvh,
                    const float* __restrict__ bconv, const __half* __restrict__ wlfch,
                    const float* __restrict__ blfc, __half* __restrict__ zcat) {
    __shared__ __half Zt[128 * 128];
    __shared__ __half As[128 * 64];
    __shared__ __half Bs[128 * 64];
    const int t = threadIdx.x;
    const int lane = t & 63, wave = t >> 6;
    const int lr = lane & 15, lg = lane >> 4;
    const int wm = wave >> 1, wn = wave & 1;
    const int m0 = blockIdx.x * 128;
    const int srow = t >> 3;
    const int scb = ((t & 7) << 4) ^ (((t >> 3) & 7) << 4);
    const int swz = (lr & 7) << 4;

    const __half* Ag = cubes + (size_t)(m0 + srow) * 128 + (scb >> 1);
    const __half* Bg = wconvh + (size_t)srow * 128 + (scb >> 1);
    __half* Al = As + wave * 512;
    __half* Bl = Bs + wave * 512;
    const char* aB = (const char*)As + (wm * 64 + lr) * 128;
    const char* bB = (const char*)Bs + (wn * 64 + lr) * 128;

    f32x4 acc[4][4] = {};
    for (int kc = 0; kc < 128; kc += 64) {
#pragma unroll
        for (int i = 0; i < 4; ++i) {
            gload_lds16(Ag + (size_t)i * 32 * 128 + kc, Al + i * 2048);
            gload_lds16(Bg + (size_t)i * 32 * 128 + kc, Bl + i * 2048);
        }
        __syncthreads();
#pragma unroll
        for (int kk = 0; kk < 2; ++kk) {
            const int ko = (kk * 64 + lg * 16) ^ swz;
            f16x8 af[4], bf[4];
#pragma unroll
            for (int fx = 0; fx < 4; ++fx) {
                af[fx] = *(const f16x8*)(aB + fx * 2048 + ko);
                bf[fx] = *(const f16x8*)(bB + fx * 2048 + ko);
            }
#pragma unroll
            for (int fm = 0; fm < 4; ++fm)
#pragma unroll
                for (int fn = 0; fn < 4; ++fn)
                    acc[fm][fn] = MFMA16(af[fm], bf[fn], acc[fm][fn]);
        }
        __syncthreads();
    }
#pragma unroll
    for (int fm = 0; fm < 4; ++fm) {
#pragma unroll
        for (int fn = 0; fn < 4; ++fn) {
            int col = wn * 64 + fn * 16 + lr;
            float bias = bconv[col];
#pragma unroll
            for (int r = 0; r < 4; ++r) {
                int row = wm * 64 + fm * 16 + lg * 4 + r;
                float val = leakyf(acc[fm][fn][r] + bias);
                *(__half*)((char*)Zt + row * 256 + ((2 * col) ^ ((row & 7) << 4))) = __float2half(val);
            }
        }
    }
    __syncthreads();

    const __half* Bg2 = wlfch + (size_t)srow * 128 + (scb >> 1);
    const char* zR = (const char*)Zt + (wm * 64 + lr) * 256;
    f32x4 acc2[4][4] = {};
    for (int kc = 0; kc < 128; kc += 64) {
#pragma unroll
        for (int i = 0; i < 4; ++i)
            gload_lds16(Bg2 + (size_t)i * 32 * 128 + kc, Bl + i * 2048);
        __syncthreads();
#pragma unroll
        for (int kk = 0; kk < 2; ++kk) {
            const int kb = kc * 2 + kk * 64 + lg * 16;
            const int ko = (kk * 64 + lg * 16) ^ swz;
            f16x8 af[4], bf[4];
#pragma unroll
            for (int fx = 0; fx < 4; ++fx) {
                af[fx] = *(const f16x8*)(zR + fx * 4096 + (kb ^ swz));
                bf[fx] = *(const f16x8*)(bB + fx * 2048 + ko);
            }
#pragma unroll
            for (int fm = 0; fm < 4; ++fm)
#pragma unroll
                for (int fn = 0; fn < 4; ++fn)
                    acc2[fm][fn] = MFMA16(af[fm], bf[fn], acc2[fm][fn]);
        }
        __syncthreads();
    }
#pragma unroll
    for (int fm = 0; fm < 4; ++fm) {
#pragma unroll
        for (int fn = 0; fn < 4; ++fn) {
            int col = wn * 64 + fn * 16 + lr;
            float bias = blfc[col];
#pragma unroll
            for (int r = 0; r < 4; ++r) {
                int row = m0 + wm * 64 + fm * 16 + lg * 4 + r;
                zcat[(size_t)row * 256 + 128 + col] = __float2half(leakyf(acc2[fm][fn][r] + bias));
            }
        }
    }
}

// ---------- 16-wave GEMM: 256m x 256n block, 1024 threads, waves 4x4 ----------
// Same per-wave 64x64 acc[4][4] fragment math / swizzle / staging involution as
// the proven gemm_wide8; only constants scale (half the blocks again -> half
// the total K-steps; per-thread staging 6->4 chunks; 64KB LDS -> 2 blocks/CU =
// 32 waves/CU).  Passes advance 128 rows (128%8==0, swizzle row-phase holds).
template<bool F32OUT>
__global__ __launch_bounds__(1024)
void gemm_wide16(const __half* __restrict__ A, const __half* __restrict__ W,
                 const float* __restrict__ bias, void* __restrict__ outp,
                 int K, int Meff, int OS, int OC, const int* __restrict__ rowmap) {
    __shared__ __half As[16384];   // 256 x 64 fp16, swizzled rows (32KB)
    __shared__ __half Bs[16384];   // 256 x 64 fp16, swizzled rows (32KB)
    const int t = threadIdx.x;
    const int lane = t & 63, wave = t >> 6;    // 0..15
    const int lr = lane & 15, lg = lane >> 4;
    const int wm = wave >> 2, wn = wave & 3;   // 4 x 4 wave grid
    const int m0 = blockIdx.x * 256, n0 = blockIdx.y * 256;

    const int srow = t >> 3;                   // 0..127; passes advance 128 rows
    const int scb = ((t & 7) << 4) ^ (((t >> 3) & 7) << 4);
    const __half* Ag = A + (size_t)(m0 + srow) * K + (scb >> 1);
    const __half* Wg = W + (size_t)(n0 + srow) * K + (scb >> 1);
    __half* Al = As + wave * 512;              // wave-uniform base (1KB/wave)
    __half* Bl = Bs + wave * 512;

    const int swz = (lr & 7) << 4;
    const char* aB = (const char*)As + (wm * 64 + lr) * 128;
    const char* bB = (const char*)Bs + (wn * 64 + lr) * 128;
    const int k0 = (lg * 16) ^ swz;
    const int k1 = (64 + lg * 16) ^ swz;

    f32x4 acc[4][4] = {};

    for (int kc = 0; kc < K; kc += 64) {
#pragma unroll
        for (int i = 0; i < 2; ++i)     // A: 2 passes x 128 rows (16KB each)
            gload_lds16(Ag + (size_t)i * 128 * K + kc, Al + i * 8192);
#pragma unroll
        for (int i = 0; i < 2; ++i)     // B: 2 passes x 128 rows
            gload_lds16(Wg + (size_t)i * 128 * K + kc, Bl + i * 8192);
        __syncthreads();
        f16x8 af[4], bf[4];
#pragma unroll
        for (int fx = 0; fx < 4; ++fx) {
            af[fx] = *(const f16x8*)(aB + fx * 2048 + k0);
            bf[fx] = *(const f16x8*)(bB + fx * 2048 + k0);
        }
#pragma unroll
        for (int fm = 0; fm < 4; ++fm)
#pragma unroll
            for (int fn = 0; fn < 4; ++fn)
                acc[fm][fn] = MFMA16(af[fm], bf[fn], acc[fm][fn]);
#pragma unroll
        for (int fx = 0; fx < 4; ++fx) {
            af[fx] = *(const f16x8*)(aB + fx * 2048 + k1);
            bf[fx] = *(const f16x8*)(bB + fx * 2048 + k1);
        }
#pragma unroll
        for (int fm = 0; fm < 4; ++fm)
#pragma unroll
            for (int fn = 0; fn < 4; ++fn)
                acc[fm][fn] = MFMA16(af[fm], bf[fn], acc[fm][fn]);
        __syncthreads();
    }

    float bv[4];
#pragma unroll
    for (int fn = 0; fn < 4; ++fn) bv[fn] = bias[n0 + wn * 64 + fn * 16 + lr];
    const int rbase = m0 + wm * 64 + lg * 4;
    const int cbase = OC + n0 + wn * 64 + lr;
#pragma unroll
    for (int fm = 0; fm < 4; ++fm) {
#pragma unroll
        for (int r = 0; r < 4; ++r) {
            int row = rbase + fm * 16 + r;
            if (row < Meff) {
                size_t orow = (size_t)(rowmap ? rowmap[row] : row);
#pragma unroll
                for (int fn = 0; fn < 4; ++fn) {
                    float val = leakyf(acc[fm][fn][r] + bv[fn]);
                    if (F32OUT)
                        ((float*)outp)[orow * OS + cbase + fn * 16] = val;
                    else
                        ((__half*)outp)[orow * OS + cbase + fn * 16] = __float2half(val);
                }
            }
        }
    }
}

extern "C" void kernel_launch(void* const* d_in, const int* in_sizes, int n_in,
                              void* d_out, int out_size, void* d_ws, size_t ws_size,
                              hipStream_t stream) {
    const float* v = (const float*)d_in[0];
    const int* f = (const int*)d_in[1];
    const float* vol = (const float*)d_in[2];
    const float* Wconv = (const float*)d_in[3];
    const float* bconv = (const float*)d_in[4];
    const float* Wlfc = (const float*)d_in[5];
    const float* blfc = (const float*)d_in[6];
    const float* W1 = (const float*)d_in[7];
    const float* b1 = (const float*)d_in[8];
    const float* W2 = (const float*)d_in[9];
    const float* b2 = (const float*)d_in[10];
    const float* W3 = (const float*)d_in[11];
    const float* b3 = (const float*)d_in[12];
    float* out = (float*)d_out;
    const int M = in_sizes[0] / 3;
    const int NF = in_sizes[1] / 3;
    const int NE = 3 * NF;
    const int NB = (NE + 4095) / 4096;

    char* base = (char*)d_ws;
    float* vn = (float*)base;
    size_t off = ((size_t)M * 12 + 255) & ~(size_t)255;
    int* codes = (int*)(base + off); off += ((size_t)M * 4 + 255) & ~(size_t)255;
    int* perm  = (int*)(base + off); off += ((size_t)M * 4 + 255) & ~(size_t)255;
    int* hist  = (int*)(base + off); off += 4096 * 4;
    int* offs  = (int*)(base + off); off += 4096 * 4;
    float4* fn4 = (float4*)(base + off); off += (size_t)NF * 16;
    unsigned* sortedV = (unsigned*)(base + off); off += ((size_t)NE * 4 + 255) & ~(size_t)255;
    unsigned* sortedE = (unsigned*)(base + off); off += ((size_t)NE * 4 + 255) & ~(size_t)255;
    unsigned* gh = (unsigned*)(base + off); off += ((size_t)1024 * NB * 4 + 255) & ~(size_t)255;
    unsigned* binstart = (unsigned*)(base + off); off += 1032 * 4;
    unsigned* binTotals = (unsigned*)(base + off); off += 1024 * 4;
    __half* wpadh = (__half*)(base + off); off += 32768;
    __half* wlfch = (__half*)(base + off); off += 32768;
    __half* w2h = (__half*)(base + off); off += 262144;
    __half* w3h = (__half*)(base + off); off += 262144;
    size_t avail = ws_size > off ? ws_size - off : 0;
    size_t Mpad = ((size_t)M + 255) & ~(size_t)255;   // 256-row tiles
    size_t chm = (avail / 1792) & ~(size_t)255;
    if (chm > Mpad) chm = Mpad;
    if (chm < 256) chm = 256;
    const bool single = (chm >= (size_t)M);  // single-chunk: original-order rows
    __half* cubes = (__half*)(base + off);
    __half* zcat = cubes + chm * 128;
    __half* h = zcat + chm * 256;

    const int fnB = (NF + 255) / 256;
    const int chB = (M + 255) / 256;

    hipMemsetAsync(hist, 0, 4096 * 4, stream);
    // prelude1: fn | inc_hist | code_hist | prep_weights
    prelude1_kernel<<<fnB + NB + chB + 1152, 256, 0, stream>>>(
        v, f, fn4, NF, NE, gh, fnB, NB, chB, codes, hist, M,
        Wconv, Wlfc, W2, W3, wpadh, wlfch, w2h, w3h);
    // prelude2: row scans (incidence bins) | morton hist scan
    prelude2_kernel<<<1025, 256, 0, stream>>>(gh, binTotals, NB, hist, offs);
    // prelude3: bin scan | morton scatter
    prelude3_kernel<<<1 + chB, 256, 0, stream>>>(binTotals, binstart, codes, offs, perm, M);
    inc_scatter_kernel<<<NB, 256, 0, stream>>>(f, gh, binstart, sortedV, sortedE, NE);
    vn_gather_kernel<<<(M + 255) / 256, 256, 0, stream>>>(sortedV, sortedE, fn4, binstart, vn, M);

    for (size_t ms = 0; ms < (size_t)M; ms += chm) {
        size_t rem = (size_t)M - ms;
        int cnt = (int)(rem < chm ? rem : chm);
        int mb = (cnt + 127) / 128;
        int mb256 = (cnt + 255) / 256;
        int nblk = (cnt + 1) / 2;
        // sample reads morton-ordered vertices; scatter-writes original-id rows
        sample_kernel<<<nblk, 256, 0, stream>>>(v, vol, perm, cubes, (int)ms, cnt, nblk,
                                                single ? 1 : 0);
        convlfc_kernel<<<mb, 256, 0, stream>>>(cubes, wpadh, bconv, wlfch, blfc, zcat);
        point_kernel<<<(cnt + 1) / 2, 256, 0, stream>>>(
            v, vn, single ? nullptr : perm, W1, b1, zcat, (int)ms, cnt);
        // h = leaky(zcat @ W2^T + b2)   K=256, N=512 (2 n-tiles of 256)
        gemm_wide16<false><<<dim3(mb256, 2), 1024, 0, stream>>>(
            zcat, w2h, b2, h, 256, mb256 * 256, 512, 0, nullptr);
        // out = leaky(h @ W3^T + b3)    K=512, N=256 (single n-tile)
        gemm_wide16<true><<<dim3(mb256, 1), 1024, 0, stream>>>(
            h, w3h, b3, out, 512, cnt, 256, 0, single ? nullptr : (perm + ms));
    }
}

// Round 27
// 460.403 us; speedup vs baseline: 1.0457x; 1.0457x over previous
//
#include <hip/hip_runtime.h>
#include <hip/hip_fp16.h>

#define NEG_SLOPE 0.2f

using f16x8 = __attribute__((ext_vector_type(8))) _Float16;
using f32x4 = __attribute__((ext_vector_type(4))) float;

__device__ __forceinline__ float leakyf(float x) { return x >= 0.f ? x : NEG_SLOPE * x; }

__device__ __forceinline__ void gload_lds16(const void* g, void* l) {
    __builtin_amdgcn_global_load_lds(
        (const __attribute__((address_space(1))) unsigned int*)g,
        (__attribute__((address_space(3))) unsigned int*)l, 16, 0, 0);
}

#define MFMA16(a, b, c) __builtin_amdgcn_mfma_f32_16x16x32_f16(a, b, c, 0, 0, 0)

// ===== prelude1: fn | inc_hist | code_hist | prep_weights (independent) =====
__global__ __launch_bounds__(256)
void prelude1_kernel(const float* __restrict__ v, const int* __restrict__ f,
                     float4* __restrict__ fn4, int NF, int NE,
                     unsigned* __restrict__ gh, int fnB, int ihB, int chB,
                     int* __restrict__ codes, int* __restrict__ hist, int M,
                     const float* __restrict__ Wconv, const float* __restrict__ Wlfc,
                     const float* __restrict__ W2, const float* __restrict__ W3,
                     __half* __restrict__ wpadh, __half* __restrict__ wlfch,
                     __half* __restrict__ w2h, __half* __restrict__ w3h) {
    __shared__ unsigned h[1024];
    const int t = threadIdx.x;
    int b = blockIdx.x;
    if (b < fnB) {
        int i = b * 256 + t;
        if (i >= NF) return;
        int i0 = f[3 * i], i1 = f[3 * i + 1], i2 = f[3 * i + 2];
        float p0x = v[3 * i0], p0y = v[3 * i0 + 1], p0z = v[3 * i0 + 2];
        float ux = v[3 * i1] - p0x, uy = v[3 * i1 + 1] - p0y, uz = v[3 * i1 + 2] - p0z;
        float wx = v[3 * i2] - p0x, wy = v[3 * i2 + 1] - p0y, wz = v[3 * i2 + 2] - p0z;
        fn4[i] = make_float4(uy * wz - uz * wy, uz * wx - ux * wz, ux * wy - uy * wx, 0.f);
    } else if (b < fnB + ihB) {
        int blk = b - fnB;
        h[t] = 0; h[t + 256] = 0; h[t + 512] = 0; h[t + 768] = 0;
        __syncthreads();
        int base = blk * 4096;
#pragma unroll
        for (int k = 0; k < 16; ++k) {
            int idx = base + k * 256 + t;
            if (idx < NE) atomicAdd(&h[((unsigned)f[idx]) >> 8], 1u);
        }
        __syncthreads();
#pragma unroll
        for (int k = 0; k < 4; ++k) { int bb = t + k * 256; gh[(size_t)blk * 1024 + bb] = h[bb]; }
    } else if (b < fnB + ihB + chB) {
        int i = (b - fnB - ihB) * 256 + t;
        if (i >= M) return;
        int cx = min(max((int)((v[3 * i + 0] + 1.f) * 8.f), 0), 15);
        int cy = min(max((int)((v[3 * i + 1] + 1.f) * 8.f), 0), 15);
        int cz = min(max((int)((v[3 * i + 2] + 1.f) * 8.f), 0), 15);
        int code = 0;
#pragma unroll
        for (int bb = 0; bb < 4; ++bb)
            code |= (((cx >> bb) & 1) << (3 * bb)) | (((cy >> bb) & 1) << (3 * bb + 1)) |
                    (((cz >> bb) & 1) << (3 * bb + 2));
        codes[i] = code;
        atomicAdd(&hist[code], 1);
    } else {
        int bw = b - fnB - ihB - chB;
        if (bw < 64) {
            int i = bw * 256 + t; int ch = i >> 7, k = i & 127;
            wpadh[i] = __float2half(k < 125 ? Wconv[ch * 125 + k] : 0.f);
        } else if (bw < 128) {
            int i = (bw - 64) * 256 + t; wlfch[i] = __float2half(Wlfc[i]);
        } else if (bw < 640) {
            int i = (bw - 128) * 256 + t; w2h[i] = __float2half(W2[i]);
        } else {
            int i = (bw - 640) * 256 + t; w3h[i] = __float2half(W3[i]);
        }
    }
}

// ===== prelude2: per-bin row scan (blocks 0..1023) | morton hist scan (block 1024) =====
__global__ __launch_bounds__(256)
void prelude2_kernel(unsigned* __restrict__ gh, unsigned* __restrict__ binTotals, int NB,
                     const int* __restrict__ hist, int* __restrict__ offs) {
    __shared__ unsigned s[256];
    __shared__ unsigned carrySh;
    const int t = threadIdx.x;
    if (blockIdx.x < 1024) {
        const int bin = blockIdx.x;
        if (t == 0) carrySh = 0;
        __syncthreads();
        for (int base = 0; base < NB; base += 256) {
            unsigned c = carrySh;
            int i = base + t;
            unsigned val = (i < NB) ? gh[(size_t)i * 1024 + bin] : 0;
            s[t] = val;
            __syncthreads();
            for (int d = 1; d < 256; d <<= 1) {
                unsigned x = (t >= d) ? s[t - d] : 0;
                __syncthreads();
                s[t] += x;
                __syncthreads();
            }
            if (i < NB) gh[(size_t)i * 1024 + bin] = s[t] - val + c;
            if (t == 255) carrySh = c + s[255];
            __syncthreads();
        }
        if (t == 0) binTotals[bin] = carrySh;
    } else {
        if (t == 0) carrySh = 0;
        __syncthreads();
        for (int base = 0; base < 4096; base += 256) {
            unsigned c = carrySh;
            unsigned val = (unsigned)hist[base + t];
            s[t] = val;
            __syncthreads();
            for (int d = 1; d < 256; d <<= 1) {
                unsigned x = (t >= d) ? s[t - d] : 0;
                __syncthreads();
                s[t] += x;
                __syncthreads();
            }
            offs[base + t] = (int)(s[t] - val + c);
            if (t == 255) carrySh = c + s[255];
            __syncthreads();
        }
    }
}

// ===== prelude3: bin scan (block 0) | morton scatter (blocks 1..) =====
__global__ __launch_bounds__(256)
void prelude3_kernel(const unsigned* __restrict__ binTotals, unsigned* __restrict__ binstart,
                     const int* __restrict__ codes, int* __restrict__ offs,
                     int* __restrict__ perm, int M) {
    __shared__ unsigned s[256];
    __shared__ unsigned carrySh;
    const int t = threadIdx.x;
    if (blockIdx.x == 0) {
        if (t == 0) carrySh = 0;
        __syncthreads();
        for (int base = 0; base < 1024; base += 256) {
            unsigned c = carrySh;
            unsigned val = binTotals[base + t];
            s[t] = val;
            __syncthreads();
            for (int d = 1; d < 256; d <<= 1) {
                unsigned x = (t >= d) ? s[t - d] : 0;
                __syncthreads();
                s[t] += x;
                __syncthreads();
            }
            binstart[base + t] = s[t] - val + c;
            if (t == 255) carrySh = c + s[255];
            __syncthreads();
        }
        if (t == 0) binstart[1024] = carrySh;
    } else {
        int i = (blockIdx.x - 1) * 256 + t;
        if (i >= M) return;
        int pos = atomicAdd(&offs[codes[i]], 1);
        perm[pos] = i;
    }
}

// ===== incidence scatter (needs gh + binstart) =====
__global__ __launch_bounds__(256)
void inc_scatter_kernel(const int* __restrict__ f, const unsigned* __restrict__ gh,
                        const unsigned* __restrict__ binstart,
                        unsigned* __restrict__ sortedV, unsigned* __restrict__ sortedE,
                        int NE) {
    __shared__ unsigned loc[1024];
    const int t = threadIdx.x, blk = blockIdx.x;
#pragma unroll
    for (int k = 0; k < 4; ++k) {
        int b = t + k * 256;
        loc[b] = gh[(size_t)blk * 1024 + b] + binstart[b];
    }
    __syncthreads();
    int base = blk * 4096;
#pragma unroll
    for (int k = 0; k < 16; ++k) {
        int idx = base + k * 256 + t;
        if (idx < NE) {
            unsigned vv = (unsigned)f[idx];
            unsigned pos = atomicAdd(&loc[vv >> 8], 1u);
            sortedV[pos] = vv;
            sortedE[pos] = (unsigned)idx;
        }
    }
}

// ---- per-bin gather: LDS float accumulate, coalesced non-atomic vn write ----
__global__ __launch_bounds__(256)
void vn_gather_kernel(const unsigned* __restrict__ sortedV, const unsigned* __restrict__ sortedE,
                      const float4* __restrict__ fn4, const unsigned* __restrict__ binstart,
                      float* __restrict__ vn, int M) {
    __shared__ float acc[768];
    const int t = threadIdx.x, b = blockIdx.x;
    acc[t] = 0.f; acc[t + 256] = 0.f; acc[t + 512] = 0.f;
    __syncthreads();
    unsigned s = binstart[b], e = binstart[b + 1];
    for (unsigned i = s + t; i < e; i += 256) {
        unsigned vv = sortedV[i];
        float4 fn = fn4[sortedE[i] / 3];
        int lv = (int)(vv & 255u) * 3;
        atomicAdd(&acc[lv + 0], fn.x);
        atomicAdd(&acc[lv + 1], fn.y);
        atomicAdd(&acc[lv + 2], fn.z);
    }
    __syncthreads();
    int gv = b * 256 + t;
    if (gv < M) {
        vn[3 * gv + 0] = acc[t * 3 + 0];
        vn[3 * gv + 1] = acc[t * 3 + 1];
        vn[3 * gv + 2] = acc[t * 3 + 2];
    }
}

// ------- trilinear 5x5x5 sampling: separable params + LDS bbox staging -------
__global__ __launch_bounds__(256)
void sample_kernel(const float* __restrict__ v, const float* __restrict__ vol,
                   const int* __restrict__ perm,
                   __half* __restrict__ cubes, int m_start, int cnt, int nwg, int scatter) {
    __shared__ float bbox[2][448];
    __shared__ int pi0[2][16];
    __shared__ float pw[2][16];
    const int half = threadIdx.x >> 7;
    const int q = threadIdx.x & 127;
    int q8 = nwg >> 3, r8 = nwg & 7;
    int xcd = blockIdx.x & 7, idxb = blockIdx.x >> 3;
    int bid = (xcd < r8 ? xcd * (q8 + 1) : r8 * (q8 + 1) + (xcd - r8) * q8) + idxb;
    int ml = bid * 2 + half;
    bool valid = ml < cnt;
    int m = valid ? perm[m_start + ml] : 0;

    if (valid && q < 15) {
        int axis = q / 5, idx = q - 5 * axis;
        float g = -3.f + 1.25f * (float)idx;
        float p = v[3 * m + axis] + g / 192.f * 2.f;
        float pos = fminf(fmaxf((p + 1.f) * 0.5f * 191.f, 0.f), 191.f);
        float fl = floorf(pos);
        pi0[half][q] = (int)fl;
        pw[half][q] = pos - fl;
    }
    __syncthreads();
    if (valid) {
        int xlo = pi0[half][0], ylo = pi0[half][5], zlo = pi0[half][10];
        int j = q & 63;
        int dy = j >> 3, dx = j & 7;
        if (dy < 7) {
            int X = min(xlo + dx, 191);
            int Y = min(ylo + dy, 191);
            int rowoff = dy * 9 + dx;
            const float* volYX = vol + Y * 192 + X;
#pragma unroll
            for (int k = 0; k < 4; ++k) {
                int pz = (q >> 6) + k * 2;
                if (pz < 7) {
                    int Z = min(zlo + pz, 191);
                    bbox[half][pz * 63 + rowoff] = volYX[Z * 36864];
                }
            }
        }
    }
    __syncthreads();
    if (!valid) return;
    __half* dst = cubes + (size_t)(scatter ? m : ml) * 128;
    if (q >= 125) { dst[q] = __float2half(0.f); return; }
    int a = q % 5, b = (q / 5) % 5, c = q / 25;
    int xlo = pi0[half][0], ylo = pi0[half][5], zlo = pi0[half][10];
    int gx0 = pi0[half][a], gy0 = pi0[half][5 + b], gz0 = pi0[half][10 + c];
    float wxv = pw[half][a], wyv = pw[half][5 + b], wzv = pw[half][10 + c];
    int x0 = gx0 - xlo, y0 = gy0 - ylo, z0 = gz0 - zlo;
    int x1 = min(gx0 + 1, 191) - xlo;
    int y1 = min(gy0 + 1, 191) - ylo;
    int z1 = min(gz0 + 1, 191) - zlo;
    const float* bb = bbox[half];
    int b00 = z0 * 63 + y0 * 9, b01 = z0 * 63 + y1 * 9;
    int b10 = z1 * 63 + y0 * 9, b11 = z1 * 63 + y1 * 9;
    float c000 = bb[b00 + x0], c001 = bb[b00 + x1];
    float c010 = bb[b01 + x0], c011 = bb[b01 + x1];
    float c100 = bb[b10 + x0], c101 = bb[b10 + x1];
    float c110 = bb[b11 + x0], c111 = bb[b11 + x1];
    float omx = 1.f - wxv, omy = 1.f - wyv, omz = 1.f - wzv;
    float c00 = c000 * omx + c001 * wxv;
    float c01 = c010 * omx + c011 * wxv;
    float c10 = c100 * omx + c101 * wxv;
    float c11 = c110 * omx + c111 * wxv;
    float c0 = c00 * omy + c01 * wyv;
    float c1 = c10 * omy + c11 * wyv;
    dst[25 * a + 5 * b + c] = __float2half(c0 * omz + c1 * wzv);
}

// ---- z_point = leaky([v, vn_norm] @ W1^T + b1) -> zcat cols [0:128) fp16 ----
__global__ __launch_bounds__(256)
void point_kernel(const float* __restrict__ v, const float* __restrict__ vn,
                  const int* __restrict__ pvec,
                  const float* __restrict__ W1, const float* __restrict__ b1,
                  __half* __restrict__ zcat, int m_start, int cnt) {
    int ml = blockIdx.x * 2 + (threadIdx.x >> 7);
    if (ml >= cnt) return;
    int n = threadIdx.x & 127;
    int m = pvec ? pvec[m_start + ml] : (m_start + ml);
    float x0 = v[3 * m], x1 = v[3 * m + 1], x2 = v[3 * m + 2];
    float nx = vn[3 * m], ny = vn[3 * m + 1], nz = vn[3 * m + 2];
    float nrm = fmaxf(sqrtf(nx * nx + ny * ny + nz * nz), 1e-6f);
    nx /= nrm; ny /= nrm; nz /= nrm;
    const float* w = W1 + n * 6;
    float z = b1[n] + x0 * w[0] + x1 * w[1] + x2 * w[2] + nx * w[3] + ny * w[4] + nz * w[5];
    zcat[(size_t)ml * 256 + n] = __float2half(leakyf(z));
}

// -------- fused conv+lfc: z_local = leaky(leaky(cubes@WconvT+bc)@WlfcT+bl) --------
__global__ __launch_bounds__(256)
void convlfc_kernel(const __half* __restrict__ cubes, const __half* __restrict__ wconvh,
                    const float* __restrict__ bconv, const __half* __restrict__ wlfch,
                    const float* __restrict__ blfc, __half* __restrict__ zcat) {
    __shared__ __half Zt[128 * 128];
    __shared__ __half As[128 * 64];
    __shared__ __half Bs[128 * 64];
    const int t = threadIdx.x;
    const int lane = t & 63, wave = t >> 6;
    const int lr = lane & 15, lg = lane >> 4;
    const int wm = wave >> 1, wn = wave & 1;
    const int m0 = blockIdx.x * 128;
    const int srow = t >> 3;
    const int scb = ((t & 7) << 4) ^ (((t >> 3) & 7) << 4);
    const int swz = (lr & 7) << 4;

    const __half* Ag = cubes + (size_t)(m0 + srow) * 128 + (scb >> 1);
    const __half* Bg = wconvh + (size_t)srow * 128 + (scb >> 1);
    __half* Al = As + wave * 512;
    __half* Bl = Bs + wave * 512;
    const char* aB = (const char*)As + (wm * 64 + lr) * 128;
    const char* bB = (const char*)Bs + (wn * 64 + lr) * 128;

    f32x4 acc[4][4] = {};
    for (int kc = 0; kc < 128; kc += 64) {
#pragma unroll
        for (int i = 0; i < 4; ++i) {
            gload_lds16(Ag + (size_t)i * 32 * 128 + kc, Al + i * 2048);
            gload_lds16(Bg + (size_t)i * 32 * 128 + kc, Bl + i * 2048);
        }
        __syncthreads();
#pragma unroll
        for (int kk = 0; kk < 2; ++kk) {
            const int ko = (kk * 64 + lg * 16) ^ swz;
            f16x8 af[4], bf[4];
#pragma unroll
            for (int fx = 0; fx < 4; ++fx) {
                af[fx] = *(const f16x8*)(aB + fx * 2048 + ko);
                bf[fx] = *(const f16x8*)(bB + fx * 2048 + ko);
            }
#pragma unroll
            for (int fm = 0; fm < 4; ++fm)
#pragma unroll
                for (int fn = 0; fn < 4; ++fn)
                    acc[fm][fn] = MFMA16(af[fm], bf[fn], acc[fm][fn]);
        }
        __syncthreads();
    }
#pragma unroll
    for (int fm = 0; fm < 4; ++fm) {
#pragma unroll
        for (int fn = 0; fn < 4; ++fn) {
            int col = wn * 64 + fn * 16 + lr;
            float bias = bconv[col];
#pragma unroll
            for (int r = 0; r < 4; ++r) {
                int row = wm * 64 + fm * 16 + lg * 4 + r;
                float val = leakyf(acc[fm][fn][r] + bias);
                *(__half*)((char*)Zt + row * 256 + ((2 * col) ^ ((row & 7) << 4))) = __float2half(val);
            }
        }
    }
    __syncthreads();

    const __half* Bg2 = wlfch + (size_t)srow * 128 + (scb >> 1);
    const char* zR = (const char*)Zt + (wm * 64 + lr) * 256;
    f32x4 acc2[4][4] = {};
    for (int kc = 0; kc < 128; kc += 64) {
#pragma unroll
        for (int i = 0; i < 4; ++i)
            gload_lds16(Bg2 + (size_t)i * 32 * 128 + kc, Bl + i * 2048);
        __syncthreads();
#pragma unroll
        for (int kk = 0; kk < 2; ++kk) {
            const int kb = kc * 2 + kk * 64 + lg * 16;
            const int ko = (kk * 64 + lg * 16) ^ swz;
            f16x8 af[4], bf[4];
#pragma unroll
            for (int fx = 0; fx < 4; ++fx) {
                af[fx] = *(const f16x8*)(zR + fx * 4096 + (kb ^ swz));
                bf[fx] = *(const f16x8*)(bB + fx * 2048 + ko);
            }
#pragma unroll
            for (int fm = 0; fm < 4; ++fm)
#pragma unroll
                for (int fn = 0; fn < 4; ++fn)
                    acc2[fm][fn] = MFMA16(af[fm], bf[fn], acc2[fm][fn]);
        }
        __syncthreads();
    }
#pragma unroll
    for (int fm = 0; fm < 4; ++fm) {
#pragma unroll
        for (int fn = 0; fn < 4; ++fn) {
            int col = wn * 64 + fn * 16 + lr;
            float bias = blfc[col];
#pragma unroll
            for (int r = 0; r < 4; ++r) {
                int row = m0 + wm * 64 + fm * 16 + lg * 4 + r;
                zcat[(size_t)row * 256 + 128 + col] = __float2half(leakyf(acc2[fm][fn][r] + bias));
            }
        }
    }
}

// ---------- 8-wave GEMM: 128m x 256n block, 512 threads, waves 2x4 [r25-proven] ----------
template<bool F32OUT>
__global__ __launch_bounds__(512)
void gemm_wide8(const __half* __restrict__ A, const __half* __restrict__ W,
                const float* __restrict__ bias, void* __restrict__ outp,
                int K, int Meff, int OS, int OC, const int* __restrict__ rowmap) {
    __shared__ __half As[8192];    // 128 x 64 fp16, swizzled rows
    __shared__ __half Bs[16384];   // 256 x 64 fp16, swizzled rows
    const int t = threadIdx.x;
    const int lane = t & 63, wave = t >> 6;    // 0..7
    const int lr = lane & 15, lg = lane >> 4;
    const int wm = wave >> 2, wn = wave & 3;   // 2 x 4 wave grid
    const int m0 = blockIdx.x * 128, n0 = blockIdx.y * 256;

    const int srow = t >> 3;                   // 0..63; passes advance 64 rows
    const int scb = ((t & 7) << 4) ^ (((t >> 3) & 7) << 4);
    const __half* Ag = A + (size_t)(m0 + srow) * K + (scb >> 1);
    const __half* Wg = W + (size_t)(n0 + srow) * K + (scb >> 1);
    __half* Al = As + wave * 512;
    __half* Bl = Bs + wave * 512;

    const int swz = (lr & 7) << 4;
    const char* aB = (const char*)As + (wm * 64 + lr) * 128;
    const char* bB = (const char*)Bs + (wn * 64 + lr) * 128;
    const int k0 = (lg * 16) ^ swz;
    const int k1 = (64 + lg * 16) ^ swz;

    f32x4 acc[4][4] = {};

    for (int kc = 0; kc < K; kc += 64) {
#pragma unroll
        for (int i = 0; i < 2; ++i)     // A: 2 passes x 64 rows (8KB each)
            gload_lds16(Ag + (size_t)i * 64 * K + kc, Al + i * 4096);
#pragma unroll
        for (int i = 0; i < 4; ++i)     // B: 4 passes x 64 rows
            gload_lds16(Wg + (size_t)i * 64 * K + kc, Bl + i * 4096);
        __syncthreads();
        f16x8 af[4], bf[4];
#pragma unroll
        for (int fx = 0; fx < 4; ++fx) {
            af[fx] = *(const f16x8*)(aB + fx * 2048 + k0);
            bf[fx] = *(const f16x8*)(bB + fx * 2048 + k0);
        }
#pragma unroll
        for (int fm = 0; fm < 4; ++fm)
#pragma unroll
            for (int fn = 0; fn < 4; ++fn)
                acc[fm][fn] = MFMA16(af[fm], bf[fn], acc[fm][fn]);
#pragma unroll
        for (int fx = 0; fx < 4; ++fx) {
            af[fx] = *(const f16x8*)(aB + fx * 2048 + k1);
            bf[fx] = *(const f16x8*)(bB + fx * 2048 + k1);
        }
#pragma unroll
        for (int fm = 0; fm < 4; ++fm)
#pragma unroll
            for (int fn = 0; fn < 4; ++fn)
                acc[fm][fn] = MFMA16(af[fm], bf[fn], acc[fm][fn]);
        __syncthreads();
    }

    float bv[4];
#pragma unroll
    for (int fn = 0; fn < 4; ++fn) bv[fn] = bias[n0 + wn * 64 + fn * 16 + lr];
    const int rbase = m0 + wm * 64 + lg * 4;
    const int cbase = OC + n0 + wn * 64 + lr;
#pragma unroll
    for (int fm = 0; fm < 4; ++fm) {
#pragma unroll
        for (int r = 0; r < 4; ++r) {
            int row = rbase + fm * 16 + r;
            if (row < Meff) {
                size_t orow = (size_t)(rowmap ? rowmap[row] : row);
#pragma unroll
                for (int fn = 0; fn < 4; ++fn) {
                    float val = leakyf(acc[fm][fn][r] + bv[fn]);
                    if (F32OUT)
                        ((float*)outp)[orow * OS + cbase + fn * 16] = val;
                    else
                        ((__half*)outp)[orow * OS + cbase + fn * 16] = __float2half(val);
                }
            }
        }
    }
}

extern "C" void kernel_launch(void* const* d_in, const int* in_sizes, int n_in,
                              void* d_out, int out_size, void* d_ws, size_t ws_size,
                              hipStream_t stream) {
    const float* v = (const float*)d_in[0];
    const int* f = (const int*)d_in[1];
    const float* vol = (const float*)d_in[2];
    const float* Wconv = (const float*)d_in[3];
    const float* bconv = (const float*)d_in[4];
    const float* Wlfc = (const float*)d_in[5];
    const float* blfc = (const float*)d_in[6];
    const float* W1 = (const float*)d_in[7];
    const float* b1 = (const float*)d_in[8];
    const float* W2 = (const float*)d_in[9];
    const float* b2 = (const float*)d_in[10];
    const float* W3 = (const float*)d_in[11];
    const float* b3 = (const float*)d_in[12];
    float* out = (float*)d_out;
    const int M = in_sizes[0] / 3;
    const int NF = in_sizes[1] / 3;
    const int NE = 3 * NF;
    const int NB = (NE + 4095) / 4096;

    char* base = (char*)d_ws;
    float* vn = (float*)base;
    size_t off = ((size_t)M * 12 + 255) & ~(size_t)255;
    int* codes = (int*)(base + off); off += ((size_t)M * 4 + 255) & ~(size_t)255;
    int* perm  = (int*)(base + off); off += ((size_t)M * 4 + 255) & ~(size_t)255;
    int* hist  = (int*)(base + off); off += 4096 * 4;
    int* offs  = (int*)(base + off); off += 4096 * 4;
    float4* fn4 = (float4*)(base + off); off += (size_t)NF * 16;
    unsigned* sortedV = (unsigned*)(base + off); off += ((size_t)NE * 4 + 255) & ~(size_t)255;
    unsigned* sortedE = (unsigned*)(base + off); off += ((size_t)NE * 4 + 255) & ~(size_t)255;
    unsigned* gh = (unsigned*)(base + off); off += ((size_t)1024 * NB * 4 + 255) & ~(size_t)255;
    unsigned* binstart = (unsigned*)(base + off); off += 1032 * 4;
    unsigned* binTotals = (unsigned*)(base + off); off += 1024 * 4;
    __half* wpadh = (__half*)(base + off); off += 32768;
    __half* wlfch = (__half*)(base + off); off += 32768;
    __half* w2h = (__half*)(base + off); off += 262144;
    __half* w3h = (__half*)(base + off); off += 262144;
    size_t avail = ws_size > off ? ws_size - off : 0;
    size_t Mpad = ((size_t)M + 127) & ~(size_t)127;
    size_t chm = (avail / 1792) & ~(size_t)127;  // 256B cubes + 512B zcat + 1024B h
    if (chm > Mpad) chm = Mpad;
    if (chm < 128) chm = 128;
    const bool single = (chm >= (size_t)M);  // single-chunk: original-order rows
    __half* cubes = (__half*)(base + off);
    __half* zcat = cubes + chm * 128;
    __half* h = zcat + chm * 256;

    const int fnB = (NF + 255) / 256;
    const int chB = (M + 255) / 256;

    hipMemsetAsync(hist, 0, 4096 * 4, stream);
    // prelude1: fn | inc_hist | code_hist | prep_weights
    prelude1_kernel<<<fnB + NB + chB + 1152, 256, 0, stream>>>(
        v, f, fn4, NF, NE, gh, fnB, NB, chB, codes, hist, M,
        Wconv, Wlfc, W2, W3, wpadh, wlfch, w2h, w3h);
    // prelude2: row scans (incidence bins) | morton hist scan
    prelude2_kernel<<<1025, 256, 0, stream>>>(gh, binTotals, NB, hist, offs);
    // prelude3: bin scan | morton scatter
    prelude3_kernel<<<1 + chB, 256, 0, stream>>>(binTotals, binstart, codes, offs, perm, M);
    inc_scatter_kernel<<<NB, 256, 0, stream>>>(f, gh, binstart, sortedV, sortedE, NE);
    vn_gather_kernel<<<(M + 255) / 256, 256, 0, stream>>>(sortedV, sortedE, fn4, binstart, vn, M);

    for (size_t ms = 0; ms < (size_t)M; ms += chm) {
        size_t rem = (size_t)M - ms;
        int cnt = (int)(rem < chm ? rem : chm);
        int mb = (cnt + 127) / 128;
        int nblk = (cnt + 1) / 2;
        // sample reads morton-ordered vertices; scatter-writes original-id rows
        sample_kernel<<<nblk, 256, 0, stream>>>(v, vol, perm, cubes, (int)ms, cnt, nblk,
                                                single ? 1 : 0);
        convlfc_kernel<<<mb, 256, 0, stream>>>(cubes, wpadh, bconv, wlfch, blfc, zcat);
        point_kernel<<<(cnt + 1) / 2, 256, 0, stream>>>(
            v, vn, single ? nullptr : perm, W1, b1, zcat, (int)ms, cnt);
        // h = leaky(zcat @ W2^T + b2)   K=256, N=512 (2 n-tiles of 256)
        gemm_wide8<false><<<dim3(mb, 2), 512, 0, stream>>>(
            zcat, w2h, b2, h, 256, mb * 128, 512, 0, nullptr);
        // out = leaky(h @ W3^T + b3)    K=512, N=256 (single n-tile)
        gemm_wide8<true><<<dim3(mb, 1), 512, 0, stream>>>(
            h, w3h, b3, out, 512, cnt, 256, 0, single ? nullptr : (perm + ms));
    }
}